// Round 16
// baseline (437.342 us; speedup 1.0000x reference)
//
#include <hip/hip_runtime.h>

#define D 512
#define T 2048
#define BATCH 8
#define M_ROWS (BATCH*T)   // 16384
#define CHK 64             // chunk length
#define NCHB 32            // chunks per batch
#define NCHUNK 256         // total chunks

typedef __attribute__((ext_vector_type(8))) short short8;
typedef __attribute__((ext_vector_type(4))) float floatx4;

__device__ __forceinline__ unsigned short f2bf(float f) {
  unsigned int u = __float_as_uint(f);
  u += 0x7FFFu + ((u >> 16) & 1u);          // RNE
  return (unsigned short)(u >> 16);
}
__device__ __forceinline__ float bf2f(unsigned int h) {
  return __uint_as_float(h << 16);
}
__device__ __forceinline__ float wave_allreduce(float v) {
  #pragma unroll
  for (int m = 32; m; m >>= 1) v += __shfl_xor(v, m, 64);
  return v;
}
__device__ __forceinline__ void unpack8(uint4 r, float f[8]) {
  f[0] = bf2f(r.x & 0xffffu); f[1] = bf2f(r.x >> 16);
  f[2] = bf2f(r.y & 0xffffu); f[3] = bf2f(r.y >> 16);
  f[4] = bf2f(r.z & 0xffffu); f[5] = bf2f(r.z >> 16);
  f[6] = bf2f(r.w & 0xffffu); f[7] = bf2f(r.w >> 16);
}

// async global->LDS 16B per lane; lds base must be wave-uniform (HW adds lane*16)
typedef const __attribute__((address_space(1))) void* gas_ptr;
typedef __attribute__((address_space(3))) void* lds_ptr;
__device__ __forceinline__ void gld16(const void* g, void* l) {
  __builtin_amdgcn_global_load_lds((gas_ptr)g, (lds_ptr)l, 16, 0, 0);
}

// keep-alive: data dependence on the loaded VALUE (rule #17). Forces the load
// to be complete at this point; clustering keep-alives batches the loads.
__device__ __forceinline__ void ka(short8 v) { asm volatile("" :: "v"(v)); }

// ---------------- fused f32 -> bf16 cast: x (4096 blocks) + 4 weight mats (512 blocks) ----------------
__global__ __launch_bounds__(256) void cast_all(
    const float* __restrict__ x,
    const float* __restrict__ Wq, const float* __restrict__ Wk,
    const float* __restrict__ Wv, const float* __restrict__ Wo,
    unsigned short* __restrict__ Xb, unsigned short* __restrict__ Wqb) {
  int blk = blockIdx.x;
  const float* src;
  unsigned short* dst;
  int idx;
  if (blk < 4096) {
    src = x; dst = Xb; idx = blk * 2048 + threadIdx.x * 8;
  } else {
    int b2 = blk - 4096;
    int sel = b2 >> 7;
    src = (sel == 0) ? Wq : (sel == 1) ? Wk : (sel == 2) ? Wv : Wo;
    dst = Wqb + (size_t)sel * (D * D);
    idx = (b2 & 127) * 2048 + threadIdx.x * 8;
  }
  const float4* sp = (const float4*)(src + idx);
  float4 a = sp[0], b = sp[1];
  uint4 o;
  o.x = f2bf(a.x) | ((unsigned)f2bf(a.y) << 16);
  o.y = f2bf(a.z) | ((unsigned)f2bf(a.w) << 16);
  o.z = f2bf(b.x) | ((unsigned)f2bf(b.y) << 16);
  o.w = f2bf(b.z) | ((unsigned)f2bf(b.w) << 16);
  *(uint4*)(dst + idx) = o;
}

// ---------------- bf16 MFMA GEMM: C = A(MxK) * W(NxK)^T + bias ----------------
#define BM 128
#define BN 128
#define BK 32

// XCD-affinity remap: physical wg `flat` (XCD ~= flat%8) computes tile
// ty = (flat&7)*16 + j/gx, tx = j%gx  (j = flat>>3). All gx blocks sharing an
// A-row-panel land on ONE XCD -> A panel becomes L2-resident (T1 mechanism).
template<bool OUT_BF16>
__global__ __launch_bounds__(256) void gemm_nt(
    const unsigned short* __restrict__ A, const unsigned short* __restrict__ Bw,
    const float* __restrict__ bias, void* __restrict__ Cout, int M, int N, int K)
{
  __shared__ __align__(16) unsigned short As[BM * BK];
  __shared__ __align__(16) unsigned short Bs[BN * BK];
  int tid  = threadIdx.x;
  int lane = tid & 63;
  int wave = tid >> 6;
  int waveM = (wave >> 1) * 64;
  int waveN = (wave & 1) * 64;
  int lrow = lane & 15;
  int quad = lane >> 4;

  // remap (gridX=4, gridY=128): flat in [0,512), per XCD 16 y-rows x 4 x
  int flat = blockIdx.x + blockIdx.y * 4;
  int g = flat & 7, j = flat >> 3;
  int ty = g * 16 + (j >> 2);
  int tx = j & 3;

  floatx4 acc[4][4];
  #pragma unroll
  for (int a_ = 0; a_ < 4; ++a_)
    #pragma unroll
    for (int b_ = 0; b_ < 4; ++b_) acc[a_][b_] = (floatx4){0.f, 0.f, 0.f, 0.f};

  const unsigned short* Ap = A  + (size_t)(ty * BM) * K;
  const unsigned short* Bp = Bw + (size_t)(tx * BN) * K;
  int r0 = tid >> 2;
  int c0 = (tid & 3) * 8;

  unsigned short* AsW = As + (wave << 9);
  unsigned short* BsW = Bs + (wave << 9);
  const unsigned short* ApL = Ap + (size_t)r0 * K + c0;
  const unsigned short* ApH = Ap + (size_t)(r0 + 64) * K + c0;
  const unsigned short* BpL = Bp + (size_t)r0 * K + c0;
  const unsigned short* BpH = Bp + (size_t)(r0 + 64) * K + c0;

  for (int k0 = 0; k0 < K; k0 += BK) {
    __syncthreads();
    gld16(ApL + k0, AsW);
    gld16(ApH + k0, AsW + 2048);
    gld16(BpL + k0, BsW);
    gld16(BpH + k0, BsW + 2048);
    __syncthreads();
    short8 af[4], bf[4];
    #pragma unroll
    for (int mt = 0; mt < 4; ++mt)
      af[mt] = *(const short8*)&As[(waveM + mt * 16 + lrow) * BK + quad * 8];
    #pragma unroll
    for (int nt = 0; nt < 4; ++nt)
      bf[nt] = *(const short8*)&Bs[(waveN + nt * 16 + lrow) * BK + quad * 8];
    #pragma unroll
    for (int mt = 0; mt < 4; ++mt)
      #pragma unroll
      for (int nt = 0; nt < 4; ++nt)
        acc[mt][nt] = __builtin_amdgcn_mfma_f32_16x16x32_bf16(af[mt], bf[nt], acc[mt][nt], 0, 0, 0);
  }

  int cm = ty * BM + waveM;
  int cn = tx * BN + waveN;
  #pragma unroll
  for (int nt = 0; nt < 4; ++nt) {
    int col = cn + nt * 16 + lrow;
    float bv = bias[col];
    #pragma unroll
    for (int mt = 0; mt < 4; ++mt) {
      #pragma unroll
      for (int r = 0; r < 4; ++r) {
        int row = cm + mt * 16 + quad * 4 + r;
        float v = acc[mt][nt][r] + bv;
        if (OUT_BF16) ((unsigned short*)Cout)[(size_t)row * N + col] = f2bf(v);
        else          ((float*)Cout)[(size_t)row * N + col] = v;
      }
    }
  }
}

// ---------------- fused QKV GEMM (XCD-affinity remap, gridX=12) ----------------
__global__ __launch_bounds__(256) void gemm_qkv(
    const unsigned short* __restrict__ A, const unsigned short* __restrict__ Bw,
    const float* __restrict__ bq, const float* __restrict__ bk,
    const float* __restrict__ bv, unsigned short* __restrict__ Cout)
{
  __shared__ __align__(16) unsigned short As[BM * BK];
  __shared__ __align__(16) unsigned short Bs[BN * BK];
  const int K = D;
  int tid  = threadIdx.x;
  int lane = tid & 63;
  int wave = tid >> 6;
  int waveM = (wave >> 1) * 64;
  int waveN = (wave & 1) * 64;
  int lrow = lane & 15;
  int quad = lane >> 4;

  // remap (grid 12 x 128 = 1536): per XCD 16 y-rows x 12 x
  int flat = blockIdx.x + blockIdx.y * 12;
  int g = flat & 7, j = flat >> 3;        // j in [0,192)
  int ty = g * 16 + j / 12;
  int tx = j % 12;

  int mat = tx >> 2;                      // 0=Q 1=K 2=V
  const float* bias = (mat == 0) ? bq : (mat == 1 ? bk : bv);

  floatx4 acc[4][4];
  #pragma unroll
  for (int a_ = 0; a_ < 4; ++a_)
    #pragma unroll
    for (int b_ = 0; b_ < 4; ++b_) acc[a_][b_] = (floatx4){0.f, 0.f, 0.f, 0.f};

  const unsigned short* Ap = A  + (size_t)(ty * BM) * K;
  const unsigned short* Bp = Bw + (size_t)(tx * BN) * K;   // combined 1536 rows
  int r0 = tid >> 2;
  int c0 = (tid & 3) * 8;

  unsigned short* AsW = As + (wave << 9);
  unsigned short* BsW = Bs + (wave << 9);
  const unsigned short* ApL = Ap + (size_t)r0 * K + c0;
  const unsigned short* ApH = Ap + (size_t)(r0 + 64) * K + c0;
  const unsigned short* BpL = Bp + (size_t)r0 * K + c0;
  const unsigned short* BpH = Bp + (size_t)(r0 + 64) * K + c0;

  for (int k0 = 0; k0 < K; k0 += BK) {
    __syncthreads();
    gld16(ApL + k0, AsW);
    gld16(ApH + k0, AsW + 2048);
    gld16(BpL + k0, BsW);
    gld16(BpH + k0, BsW + 2048);
    __syncthreads();
    short8 af[4], bf[4];
    #pragma unroll
    for (int mt = 0; mt < 4; ++mt)
      af[mt] = *(const short8*)&As[(waveM + mt * 16 + lrow) * BK + quad * 8];
    #pragma unroll
    for (int nt = 0; nt < 4; ++nt)
      bf[nt] = *(const short8*)&Bs[(waveN + nt * 16 + lrow) * BK + quad * 8];
    #pragma unroll
    for (int mt = 0; mt < 4; ++mt)
      #pragma unroll
      for (int nt = 0; nt < 4; ++nt)
        acc[mt][nt] = __builtin_amdgcn_mfma_f32_16x16x32_bf16(af[mt], bf[nt], acc[mt][nt], 0, 0, 0);
  }

  unsigned short* outb = Cout + (size_t)mat * ((size_t)M_ROWS * D);
  int cm = ty * BM + waveM;
  int cnl = (tx & 3) * BN + waveN;
  #pragma unroll
  for (int nt = 0; nt < 4; ++nt) {
    int col = cnl + nt * 16 + lrow;
    float bvv = bias[col];
    #pragma unroll
    for (int mt = 0; mt < 4; ++mt) {
      #pragma unroll
      for (int r = 0; r < 4; ++r) {
        int row = cm + mt * 16 + quad * 4 + r;
        outb[(size_t)row * D + col] = f2bf(acc[mt][nt][r] + bvv);
      }
    }
  }
}

// ---------------- fused per-chunk transpose + K-norm + Beta ----------------
__global__ __launch_bounds__(256) void transpose_norm(
    unsigned short* __restrict__ Kb, const unsigned short* __restrict__ Vb,
    const float* __restrict__ Wbeta, const float* __restrict__ bbeta,
    float* __restrict__ Beta,
    unsigned short* __restrict__ KT, unsigned short* __restrict__ VT)
{
  __shared__ __align__(16) unsigned short Kc[64 * 520];
  int cb = blockIdx.x & 255, tid = threadIdx.x;
  bool isK = blockIdx.x < 256;
  unsigned short* dst = (isK ? KT : VT) + (size_t)cb * 32768;
  if (isK) {
    int lane = tid & 63, w = tid >> 6;
    const float* wb = Wbeta + lane * 8;
    #pragma unroll
    for (int i = 0; i < 16; ++i) {
      int row = w * 16 + i;
      unsigned short* kp = Kb + ((size_t)cb * 64 + row) * 512 + lane * 8;
      uint4 raw = *(uint4*)kp;
      float kv[8]; unpack8(raw, kv);
      float ss = 0.f;
      #pragma unroll
      for (int m = 0; m < 8; ++m) ss += kv[m] * kv[m];
      ss = wave_allreduce(ss);
      float inv = 1.0f / fmaxf(sqrtf(ss), 1e-12f);
      float dotp = 0.f;
      #pragma unroll
      for (int m = 0; m < 8; ++m) { kv[m] *= inv; dotp += kv[m] * wb[m]; }
      uint4 o;
      o.x = f2bf(kv[0]) | ((unsigned)f2bf(kv[1]) << 16);
      o.y = f2bf(kv[2]) | ((unsigned)f2bf(kv[3]) << 16);
      o.z = f2bf(kv[4]) | ((unsigned)f2bf(kv[5]) << 16);
      o.w = f2bf(kv[6]) | ((unsigned)f2bf(kv[7]) << 16);
      *(uint4*)kp = o;                                  // normalized K back to global (for gram)
      *(uint4*)&Kc[row * 520 + lane * 8] = o;           // and into LDS for the transpose
      dotp = wave_allreduce(dotp);
      if (lane == 0) Beta[cb * 64 + row] = 1.0f / (1.0f + expf(-(dotp + bbeta[0])));
    }
  } else {
    const unsigned short* src = Vb + (size_t)cb * 64 * 512;
    #pragma unroll
    for (int it = 0; it < 16; ++it) {
      int e = it * 2048 + tid * 8;
      int row = e >> 9, col = e & 511;
      *(uint4*)&Kc[row * 520 + col] = *(const uint4*)&src[row * 512 + col];
    }
  }
  __syncthreads();
  #pragma unroll
  for (int it = 0; it < 16; ++it) {
    int e = it * 2048 + tid * 8;
    int dk = e >> 6, t0 = e & 63;
    uint4 o;
    unsigned short tv[8];
    #pragma unroll
    for (int u = 0; u < 8; ++u) tv[u] = Kc[(t0 + u) * 520 + dk];
    o.x = tv[0] | ((unsigned)tv[1] << 16);
    o.y = tv[2] | ((unsigned)tv[3] << 16);
    o.z = tv[4] | ((unsigned)tv[5] << 16);
    o.w = tv[6] | ((unsigned)tv[7] << 16);
    *(uint4*)&dst[e] = o;
  }
}

// ---------------- fused Gram + Tinv ----------------
__global__ __launch_bounds__(256) void gram_tinv(
    const unsigned short* __restrict__ Qb, const unsigned short* __restrict__ Kb,
    const float* __restrict__ Beta, unsigned short* __restrict__ Msb,
    unsigned short* __restrict__ Tib)
{
  __shared__ float Af[64 * 68];    // 17.4 KB
  __shared__ float XT[64 * 68];    // 17.4 KB
  int cb = blockIdx.x, tid = threadIdx.x, lane = tid & 63, w = tid >> 6;
  int lr = lane & 15, quad = lane >> 4;
  if (tid < 64) {
    *(float4*)&Af[tid * 68 + 64] = (float4){0.f,0.f,0.f,0.f};
  }
  const unsigned short* kc = Kb + (size_t)cb * 64 * 512;
  const unsigned short* qc = Qb + (size_t)cb * 64 * 512;
  floatx4 accK[4], accQ[4];
  #pragma unroll
  for (int nt = 0; nt < 4; ++nt) { accK[nt] = (floatx4){0,0,0,0}; accQ[nt] = (floatx4){0,0,0,0}; }
  #pragma unroll
  for (int ks = 0; ks < 16; ++ks) {
    short8 ak = *(const short8*)&kc[(w * 16 + lr) * 512 + ks * 32 + quad * 8];
    short8 aq = *(const short8*)&qc[(w * 16 + lr) * 512 + ks * 32 + quad * 8];
    short8 bk[4];
    #pragma unroll
    for (int nt = 0; nt < 4; ++nt)
      bk[nt] = *(const short8*)&kc[(nt * 16 + lr) * 512 + ks * 32 + quad * 8];
    #pragma unroll
    for (int nt = 0; nt < 4; ++nt) {
      accK[nt] = __builtin_amdgcn_mfma_f32_16x16x32_bf16(ak, bk[nt], accK[nt], 0, 0, 0);
      accQ[nt] = __builtin_amdgcn_mfma_f32_16x16x32_bf16(aq, bk[nt], accQ[nt], 0, 0, 0);
    }
  }
  #pragma unroll
  for (int nt = 0; nt < 4; ++nt)
    #pragma unroll
    for (int r = 0; r < 4; ++r) {
      int t = w * 16 + quad * 4 + r;
      int j = nt * 16 + lr;
      float bt = Beta[cb * 64 + t];
      Af[t * 68 + j] = (j < t) ? bt * accK[nt][r] : 0.f;
      Msb[(size_t)cb * 4096 + t * 64 + j] = f2bf((j <= t) ? accQ[nt][r] : 0.f);
    }
  __syncthreads();
  if (tid < 64) {
    int l = tid;
    float bl = Beta[cb * 64 + l];
    unsigned short* To = Tib + (size_t)cb * 4096;
    float* Xr = XT + l * 68;
    #pragma unroll
    for (int j = 0; j < 68; j += 4) *(float4*)&Xr[j] = (float4){0.f,0.f,0.f,0.f};
    for (int t = 0; t < 64; ++t) {
      const float* Ar = Af + t * 68;
      float p0 = 0.f, p1 = 0.f, p2 = 0.f, p3 = 0.f;
      for (int jb = 0; jb < t; jb += 4) {
        float4 xv = *(const float4*)&Xr[jb];
        float4 av = *(const float4*)&Ar[jb];
        p0 = fmaf(av.x, xv.x, p0); p1 = fmaf(av.y, xv.y, p1);
        p2 = fmaf(av.z, xv.z, p2); p3 = fmaf(av.w, xv.w, p3);
      }
      float y = ((l == t) ? 1.f : 0.f) - (p0 + p1) - (p2 + p3);
      Xr[t] = y;
      To[t * 64 + l] = f2bf(y * bl);
    }
  }
}

// ---------------- Wneg = -Tinvbeta*K, Ubar = Tinvbeta*V (dd-half split, 2 blocks/CU) ----------------
__global__ __launch_bounds__(256) void wu_kernel(
    const unsigned short* __restrict__ Tib, const unsigned short* __restrict__ KT,
    const unsigned short* __restrict__ VT, unsigned short* __restrict__ Wneg,
    unsigned short* __restrict__ Ubar)
{
  __shared__ __align__(16) unsigned short WL[64 * 256];   // 32 KB
  __shared__ __align__(16) unsigned short UL[64 * 256];   // 32 KB
  int cb = blockIdx.x >> 1, half = blockIdx.x & 1;
  int tid = threadIdx.x, lane = tid & 63, w = tid >> 6;
  int lr = lane & 15, quad = lane >> 4;
  short8 af0 = *(const short8*)&Tib[(size_t)cb * 4096 + (w * 16 + lr) * 64 + quad * 8];
  short8 af1 = *(const short8*)&Tib[(size_t)cb * 4096 + (w * 16 + lr) * 64 + 32 + quad * 8];
  const unsigned short* ktc = KT + (size_t)cb * 32768 + lr * 64 + quad * 8;
  const unsigned short* vtc = VT + (size_t)cb * 32768 + lr * 64 + quad * 8;
  int tbase = w * 16 + quad * 4;
  int nt0 = half * 16;
  #pragma unroll 4
  for (int ntl = 0; ntl < 16; ++ntl) {
    int nt = nt0 + ntl;
    short8 bk0 = *(const short8*)(ktc + nt * 1024);
    short8 bk1 = *(const short8*)(ktc + nt * 1024 + 32);
    short8 bv0 = *(const short8*)(vtc + nt * 1024);
    short8 bv1 = *(const short8*)(vtc + nt * 1024 + 32);
    floatx4 z = (floatx4){0.f,0.f,0.f,0.f};
    floatx4 aw = __builtin_amdgcn_mfma_f32_16x16x32_bf16(af0, bk0, z, 0, 0, 0);
    aw = __builtin_amdgcn_mfma_f32_16x16x32_bf16(af1, bk1, aw, 0, 0, 0);
    floatx4 au = __builtin_amdgcn_mfma_f32_16x16x32_bf16(af0, bv0, z, 0, 0, 0);
    au = __builtin_amdgcn_mfma_f32_16x16x32_bf16(af1, bv1, au, 0, 0, 0);
    int bi = ntl * 2 + (lr >> 3);
    int lo = lr & 7;
    #pragma unroll
    for (int r = 0; r < 4; ++r) {
      int tt = tbase + r;
      int bis = bi ^ (tt & 7);
      WL[tt * 256 + bis * 8 + lo] = f2bf(-aw[r]);
      UL[tt * 256 + bis * 8 + lo] = f2bf(au[r]);
    }
  }
  __syncthreads();
  unsigned short* wd = Wneg + (size_t)cb * 32768 + half * 256;
  unsigned short* ud = Ubar + (size_t)cb * 32768 + half * 256;
  #pragma unroll
  for (int it = 0; it < 8; ++it) {
    int e = it * 2048 + tid * 8;
    int row = e >> 8, col = e & 255;
    int bis = (col >> 3) ^ (row & 7);
    *(uint4*)&wd[(size_t)row * 512 + col] = *(const uint4*)&WL[row * 256 + bis * 8];
    *(uint4*)&ud[(size_t)row * 512 + col] = *(const uint4*)&UL[row * 256 + bis * 8];
  }
}

// ---------------- sequential chunk scan: r1 structure + keep-alive batched prefetch ----------------
// Model: 54 loads/wave x ~250cy L2 latency, serialized because the compiler sinks
// each load to its use site (VGPR froze at 152 across fence/sched_barrier tries).
// ka(v) = asm volatile("" :: "v"(v)) creates a DATA dependence: all prefetched
// fragments must be register-resident at the keep-alive cluster after B1 ->
// loads batch there (issue together, one cascaded wait) instead of serializing.
__global__ __launch_bounds__(256, 1) void seq_kernel(
    const unsigned short* __restrict__ Wneg, const unsigned short* __restrict__ Qb,
    const unsigned short* __restrict__ Ubar, const unsigned short* __restrict__ Msb,
    const unsigned short* __restrict__ KT, unsigned short* __restrict__ Ob)
{
  __shared__ __align__(16) unsigned short Sb[16 * 520];
  __shared__ __align__(16) unsigned short Ut[16 * 72];
  int blk = blockIdx.x;
  int b = blk & 7, vs = blk >> 3;      // batch pinned to XCD b for L2 sharing
  int vg0 = vs * 16;
  int tid = threadIdx.x, lane = tid & 63, w = tid >> 6;
  int lr = lane & 15, quad = lane >> 4;

  floatx4 sacc[8];
  #pragma unroll
  for (int nt = 0; nt < 8; ++nt) sacc[nt] = (floatx4){0.f,0.f,0.f,0.f};

  short8 wn[16], qf[16], kt[16], ms[2];
  unsigned short ub[4];

  auto LD_WQ = [&](int cb) {
    const unsigned short* wr = Wneg + ((size_t)cb * 64 + w * 16 + lr) * 512 + quad * 8;
    const unsigned short* qr = Qb   + ((size_t)cb * 64 + w * 16 + lr) * 512 + quad * 8;
    #pragma unroll
    for (int ks = 0; ks < 16; ++ks) {
      wn[ks] = *(const short8*)(wr + ks * 32);
      qf[ks] = *(const short8*)(qr + ks * 32);
    }
  };
  auto LD_KM = [&](int cb) {
    const unsigned short* kr = KT + (size_t)cb * 32768 + (w * 128 + lr) * 64 + quad * 8;
    #pragma unroll
    for (int nt = 0; nt < 8; ++nt) {
      kt[nt * 2 + 0] = *(const short8*)(kr + nt * 1024);
      kt[nt * 2 + 1] = *(const short8*)(kr + nt * 1024 + 32);
    }
    const unsigned short* mr = Msb + (size_t)cb * 4096 + (w * 16 + lr) * 64 + quad * 8;
    ms[0] = *(const short8*)(mr);
    ms[1] = *(const short8*)(mr + 32);
  };
  auto LD_UB = [&](int cb) {
    const unsigned short* ur = Ubar + ((size_t)cb * 64 + w * 16 + quad * 4) * 512 + vg0 + lr;
    #pragma unroll
    for (int r = 0; r < 4; ++r) ub[r] = ur[r * 512];
  };

  int cb0 = b * NCHB;
  LD_WQ(cb0); LD_KM(cb0); LD_UB(cb0);

  for (int ch = 0; ch < NCHB; ++ch) {
    int cb = cb0 + ch;
    int cbn = cb0 + (ch + 1 < NCHB ? ch + 1 : ch);
    // phase 0: stage S^T (bf16) into LDS
    #pragma unroll
    for (int nt = 0; nt < 8; ++nt)
      #pragma unroll
      for (int r = 0; r < 4; ++r)
        Sb[(quad * 4 + r) * 520 + w * 128 + nt * 16 + lr] = f2bf(sacc[nt][r]);
    __syncthreads();
    // keep-alive cluster: all this chunk's prefetched fragments must be resident
    // HERE -> their loads batch (issue together) instead of serializing at uses.
    #pragma unroll
    for (int ks = 0; ks < 16; ++ks) { ka(wn[ks]); ka(qf[ks]); ka(kt[ks]); }
    ka(ms[0]); ka(ms[1]);
    // phase 1: U-GEMM and Q*S^T interleaved (4 independent accumulator chains)
    floatx4 du0, du1, do0, do1;
    #pragma unroll
    for (int r = 0; r < 4; ++r) du0[r] = bf2f(ub[r]);
    du1 = (floatx4){0.f,0.f,0.f,0.f};
    do0 = (floatx4){0.f,0.f,0.f,0.f};
    do1 = (floatx4){0.f,0.f,0.f,0.f};
    #pragma unroll
    for (int ks = 0; ks < 16; ++ks) {
      short8 sb = *(const short8*)&Sb[lr * 520 + ks * 32 + quad * 8];
      if (ks & 1) {
        du1 = __builtin_amdgcn_mfma_f32_16x16x32_bf16(wn[ks], sb, du1, 0, 0, 0);
        do1 = __builtin_amdgcn_mfma_f32_16x16x32_bf16(qf[ks], sb, do1, 0, 0, 0);
      } else {
        du0 = __builtin_amdgcn_mfma_f32_16x16x32_bf16(wn[ks], sb, du0, 0, 0, 0);
        do0 = __builtin_amdgcn_mfma_f32_16x16x32_bf16(qf[ks], sb, do0, 0, 0, 0);
      }
    }
    #pragma unroll
    for (int r = 0; r < 4; ++r)
      Ut[lr * 72 + w * 16 + quad * 4 + r] = f2bf(du0[r] + du1[r]);
    LD_WQ(cbn);                      // prefetch: wn/qf dead
    LD_UB(cbn);                      // prefetch: ub consumed into du0
    __syncthreads();
    // phase 2: Ms*U into O, S += U^T*K
    short8 a2_0 = *(const short8*)&Ut[lr * 72 + quad * 8];
    short8 a2_1 = *(const short8*)&Ut[lr * 72 + 32 + quad * 8];
    do0 = __builtin_amdgcn_mfma_f32_16x16x32_bf16(ms[0], a2_0, do0, 0, 0, 0);
    do1 = __builtin_amdgcn_mfma_f32_16x16x32_bf16(ms[1], a2_1, do1, 0, 0, 0);
    #pragma unroll
    for (int nt = 0; nt < 8; ++nt) {
      sacc[nt] = __builtin_amdgcn_mfma_f32_16x16x32_bf16(a2_0, kt[nt * 2 + 0], sacc[nt], 0, 0, 0);
      sacc[nt] = __builtin_amdgcn_mfma_f32_16x16x32_bf16(a2_1, kt[nt * 2 + 1], sacc[nt], 0, 0, 0);
    }
    {
      unsigned short* ob = Ob + ((size_t)cb * 64 + w * 16 + quad * 4) * 512 + vg0 + lr;
      #pragma unroll
      for (int r = 0; r < 4; ++r) ob[r * 512] = f2bf(do0[r] + do1[r]);
    }
    LD_KM(cbn);                      // prefetch: kt/ms dead
  }
}

extern "C" void kernel_launch(void* const* d_in, const int* in_sizes, int n_in,
                              void* d_out, int out_size, void* d_ws, size_t ws_size,
                              hipStream_t stream) {
  const float* x     = (const float*)d_in[0];
  const float* Wq    = (const float*)d_in[1];
  const float* bq    = (const float*)d_in[2];
  const float* Wk    = (const float*)d_in[3];
  const float* bk    = (const float*)d_in[4];
  const float* Wv    = (const float*)d_in[5];
  const float* bv    = (const float*)d_in[6];
  const float* Wbeta = (const float*)d_in[7];
  const float* bbeta = (const float*)d_in[8];
  const float* Wo    = (const float*)d_in[9];
  const float* bo    = (const float*)d_in[10];

  const size_t NE = (size_t)M_ROWS * D;   // 8,388,608
  const size_t DD = (size_t)D * D;
  unsigned short* Qb  = (unsigned short*)d_ws;
  unsigned short* Kb  = Qb + NE;          // later: Ubar
  unsigned short* Vb  = Kb + NE;          // later: O
  unsigned short* Xb  = Vb + NE;          // x bf16; later: Wneg
  unsigned short* Wqb = Xb + NE;          // Wqb|Wkb|Wvb|Wob contiguous
  unsigned short* Wkb = Wqb + DD;
  unsigned short* Wvb = Wkb + DD;
  unsigned short* Wob = Wvb + DD;
  float* Beta = (float*)(Wob + DD);                        // 16384 f32
  unsigned short* KT  = (unsigned short*)(Beta + M_ROWS);  // NE shorts
  float* Abuf = (float*)(KT + NE);                         // (unused; layout kept)
  unsigned short* Msb = (unsigned short*)(Abuf + (size_t)NCHUNK * 4096);
  unsigned short* Tib = Msb + (size_t)NCHUNK * 4096;
  unsigned short* VT  = Tib + (size_t)NCHUNK * 4096;       // NE shorts; total ~106 MB

  cast_all<<<4608, 256, 0, stream>>>(x, Wq, Wk, Wv, Wo, Xb, Wqb);

  dim3 gq(12, M_ROWS / BM);
  gemm_qkv<<<gq, 256, 0, stream>>>(Xb, Wqb, bq, bk, bv, Qb);

  transpose_norm<<<2 * NCHUNK, 256, 0, stream>>>(Kb, Vb, Wbeta, bbeta, Beta, KT, VT);
  gram_tinv<<<NCHUNK, 256, 0, stream>>>(Qb, Kb, Beta, Msb, Tib);
  wu_kernel<<<2 * NCHUNK, 256, 0, stream>>>(Tib, KT, VT, /*Wneg=*/Xb, /*Ubar=*/Kb);

  seq_kernel<<<NCHUNK, 256, 0, stream>>>(/*Wneg=*/Xb, Qb, /*Ubar=*/Kb, Msb, KT, /*O=*/Vb);

  dim3 gg(D / BN, M_ROWS / BM);  // (4, 128)
  gemm_nt<false><<<gg, 256, 0, stream>>>(Vb, Wob, bo, (float*)d_out, M_ROWS, D, D);
}

// Round 17
// 418.757 us; speedup vs baseline: 1.0444x; 1.0444x over previous
//
#include <hip/hip_runtime.h>

#define D 512
#define T 2048
#define BATCH 8
#define M_ROWS (BATCH*T)   // 16384
#define CHK 64             // chunk length
#define NCHB 32            // chunks per batch
#define NCHUNK 256         // total chunks

typedef __attribute__((ext_vector_type(8))) short short8;
typedef __attribute__((ext_vector_type(4))) float floatx4;

__device__ __forceinline__ unsigned short f2bf(float f) {
  unsigned int u = __float_as_uint(f);
  u += 0x7FFFu + ((u >> 16) & 1u);          // RNE
  return (unsigned short)(u >> 16);
}
__device__ __forceinline__ float bf2f(unsigned int h) {
  return __uint_as_float(h << 16);
}
__device__ __forceinline__ float wave_allreduce(float v) {
  #pragma unroll
  for (int m = 32; m; m >>= 1) v += __shfl_xor(v, m, 64);
  return v;
}
__device__ __forceinline__ void unpack8(uint4 r, float f[8]) {
  f[0] = bf2f(r.x & 0xffffu); f[1] = bf2f(r.x >> 16);
  f[2] = bf2f(r.y & 0xffffu); f[3] = bf2f(r.y >> 16);
  f[4] = bf2f(r.z & 0xffffu); f[5] = bf2f(r.z >> 16);
  f[6] = bf2f(r.w & 0xffffu); f[7] = bf2f(r.w >> 16);
}

// async global->LDS 16B per lane; lds base must be wave-uniform (HW adds lane*16)
typedef const __attribute__((address_space(1))) void* gas_ptr;
typedef __attribute__((address_space(3))) void* lds_ptr;
__device__ __forceinline__ void gld16(const void* g, void* l) {
  __builtin_amdgcn_global_load_lds((gas_ptr)g, (lds_ptr)l, 16, 0, 0);
}

// ---------------- fused f32 -> bf16 cast: x (4096 blocks) + 4 weight mats (512 blocks) ----------------
__global__ __launch_bounds__(256) void cast_all(
    const float* __restrict__ x,
    const float* __restrict__ Wq, const float* __restrict__ Wk,
    const float* __restrict__ Wv, const float* __restrict__ Wo,
    unsigned short* __restrict__ Xb, unsigned short* __restrict__ Wqb) {
  int blk = blockIdx.x;
  const float* src;
  unsigned short* dst;
  int idx;
  if (blk < 4096) {
    src = x; dst = Xb; idx = blk * 2048 + threadIdx.x * 8;
  } else {
    int b2 = blk - 4096;
    int sel = b2 >> 7;
    src = (sel == 0) ? Wq : (sel == 1) ? Wk : (sel == 2) ? Wv : Wo;
    dst = Wqb + (size_t)sel * (D * D);
    idx = (b2 & 127) * 2048 + threadIdx.x * 8;
  }
  const float4* sp = (const float4*)(src + idx);
  float4 a = sp[0], b = sp[1];
  uint4 o;
  o.x = f2bf(a.x) | ((unsigned)f2bf(a.y) << 16);
  o.y = f2bf(a.z) | ((unsigned)f2bf(a.w) << 16);
  o.z = f2bf(b.x) | ((unsigned)f2bf(b.y) << 16);
  o.w = f2bf(b.z) | ((unsigned)f2bf(b.w) << 16);
  *(uint4*)(dst + idx) = o;
}

// ---------------- bf16 MFMA GEMM: C = A(MxK) * W(NxK)^T + bias ----------------
#define BM 128
#define BN 128
#define BK 32

// XCD-affinity remap: physical wg `flat` (XCD ~= flat%8) computes tile
// ty = (flat&7)*16 + j/gx, tx = j%gx  (j = flat>>3). All gx blocks sharing an
// A-row-panel land on ONE XCD -> A panel becomes L2-resident (T1 mechanism).
template<bool OUT_BF16>
__global__ __launch_bounds__(256) void gemm_nt(
    const unsigned short* __restrict__ A, const unsigned short* __restrict__ Bw,
    const float* __restrict__ bias, void* __restrict__ Cout, int M, int N, int K)
{
  __shared__ __align__(16) unsigned short As[BM * BK];
  __shared__ __align__(16) unsigned short Bs[BN * BK];
  int tid  = threadIdx.x;
  int lane = tid & 63;
  int wave = tid >> 6;
  int waveM = (wave >> 1) * 64;
  int waveN = (wave & 1) * 64;
  int lrow = lane & 15;
  int quad = lane >> 4;

  // remap (gridX=4, gridY=128): flat in [0,512), per XCD 16 y-rows x 4 x
  int flat = blockIdx.x + blockIdx.y * 4;
  int g = flat & 7, j = flat >> 3;
  int ty = g * 16 + (j >> 2);
  int tx = j & 3;

  floatx4 acc[4][4];
  #pragma unroll
  for (int a_ = 0; a_ < 4; ++a_)
    #pragma unroll
    for (int b_ = 0; b_ < 4; ++b_) acc[a_][b_] = (floatx4){0.f, 0.f, 0.f, 0.f};

  const unsigned short* Ap = A  + (size_t)(ty * BM) * K;
  const unsigned short* Bp = Bw + (size_t)(tx * BN) * K;
  int r0 = tid >> 2;
  int c0 = (tid & 3) * 8;

  unsigned short* AsW = As + (wave << 9);
  unsigned short* BsW = Bs + (wave << 9);
  const unsigned short* ApL = Ap + (size_t)r0 * K + c0;
  const unsigned short* ApH = Ap + (size_t)(r0 + 64) * K + c0;
  const unsigned short* BpL = Bp + (size_t)r0 * K + c0;
  const unsigned short* BpH = Bp + (size_t)(r0 + 64) * K + c0;

  for (int k0 = 0; k0 < K; k0 += BK) {
    __syncthreads();
    gld16(ApL + k0, AsW);
    gld16(ApH + k0, AsW + 2048);
    gld16(BpL + k0, BsW);
    gld16(BpH + k0, BsW + 2048);
    __syncthreads();
    short8 af[4], bf[4];
    #pragma unroll
    for (int mt = 0; mt < 4; ++mt)
      af[mt] = *(const short8*)&As[(waveM + mt * 16 + lrow) * BK + quad * 8];
    #pragma unroll
    for (int nt = 0; nt < 4; ++nt)
      bf[nt] = *(const short8*)&Bs[(waveN + nt * 16 + lrow) * BK + quad * 8];
    #pragma unroll
    for (int mt = 0; mt < 4; ++mt)
      #pragma unroll
      for (int nt = 0; nt < 4; ++nt)
        acc[mt][nt] = __builtin_amdgcn_mfma_f32_16x16x32_bf16(af[mt], bf[nt], acc[mt][nt], 0, 0, 0);
  }

  int cm = ty * BM + waveM;
  int cn = tx * BN + waveN;
  #pragma unroll
  for (int nt = 0; nt < 4; ++nt) {
    int col = cn + nt * 16 + lrow;
    float bv = bias[col];
    #pragma unroll
    for (int mt = 0; mt < 4; ++mt) {
      #pragma unroll
      for (int r = 0; r < 4; ++r) {
        int row = cm + mt * 16 + quad * 4 + r;
        float v = acc[mt][nt][r] + bv;
        if (OUT_BF16) ((unsigned short*)Cout)[(size_t)row * N + col] = f2bf(v);
        else          ((float*)Cout)[(size_t)row * N + col] = v;
      }
    }
  }
}

// ---------------- fused QKV GEMM (XCD-affinity remap, gridX=12) ----------------
__global__ __launch_bounds__(256) void gemm_qkv(
    const unsigned short* __restrict__ A, const unsigned short* __restrict__ Bw,
    const float* __restrict__ bq, const float* __restrict__ bk,
    const float* __restrict__ bv, unsigned short* __restrict__ Cout)
{
  __shared__ __align__(16) unsigned short As[BM * BK];
  __shared__ __align__(16) unsigned short Bs[BN * BK];
  const int K = D;
  int tid  = threadIdx.x;
  int lane = tid & 63;
  int wave = tid >> 6;
  int waveM = (wave >> 1) * 64;
  int waveN = (wave & 1) * 64;
  int lrow = lane & 15;
  int quad = lane >> 4;

  // remap (grid 12 x 128 = 1536): per XCD 16 y-rows x 12 x
  int flat = blockIdx.x + blockIdx.y * 12;
  int g = flat & 7, j = flat >> 3;        // j in [0,192)
  int ty = g * 16 + j / 12;
  int tx = j % 12;

  int mat = tx >> 2;                      // 0=Q 1=K 2=V
  const float* bias = (mat == 0) ? bq : (mat == 1 ? bk : bv);

  floatx4 acc[4][4];
  #pragma unroll
  for (int a_ = 0; a_ < 4; ++a_)
    #pragma unroll
    for (int b_ = 0; b_ < 4; ++b_) acc[a_][b_] = (floatx4){0.f, 0.f, 0.f, 0.f};

  const unsigned short* Ap = A  + (size_t)(ty * BM) * K;
  const unsigned short* Bp = Bw + (size_t)(tx * BN) * K;   // combined 1536 rows
  int r0 = tid >> 2;
  int c0 = (tid & 3) * 8;

  unsigned short* AsW = As + (wave << 9);
  unsigned short* BsW = Bs + (wave << 9);
  const unsigned short* ApL = Ap + (size_t)r0 * K + c0;
  const unsigned short* ApH = Ap + (size_t)(r0 + 64) * K + c0;
  const unsigned short* BpL = Bp + (size_t)r0 * K + c0;
  const unsigned short* BpH = Bp + (size_t)(r0 + 64) * K + c0;

  for (int k0 = 0; k0 < K; k0 += BK) {
    __syncthreads();
    gld16(ApL + k0, AsW);
    gld16(ApH + k0, AsW + 2048);
    gld16(BpL + k0, BsW);
    gld16(BpH + k0, BsW + 2048);
    __syncthreads();
    short8 af[4], bf[4];
    #pragma unroll
    for (int mt = 0; mt < 4; ++mt)
      af[mt] = *(const short8*)&As[(waveM + mt * 16 + lrow) * BK + quad * 8];
    #pragma unroll
    for (int nt = 0; nt < 4; ++nt)
      bf[nt] = *(const short8*)&Bs[(waveN + nt * 16 + lrow) * BK + quad * 8];
    #pragma unroll
    for (int mt = 0; mt < 4; ++mt)
      #pragma unroll
      for (int nt = 0; nt < 4; ++nt)
        acc[mt][nt] = __builtin_amdgcn_mfma_f32_16x16x32_bf16(af[mt], bf[nt], acc[mt][nt], 0, 0, 0);
  }

  unsigned short* outb = Cout + (size_t)mat * ((size_t)M_ROWS * D);
  int cm = ty * BM + waveM;
  int cnl = (tx & 3) * BN + waveN;
  #pragma unroll
  for (int nt = 0; nt < 4; ++nt) {
    int col = cnl + nt * 16 + lrow;
    float bvv = bias[col];
    #pragma unroll
    for (int mt = 0; mt < 4; ++mt) {
      #pragma unroll
      for (int r = 0; r < 4; ++r) {
        int row = cm + mt * 16 + quad * 4 + r;
        outb[(size_t)row * D + col] = f2bf(acc[mt][nt][r] + bvv);
      }
    }
  }
}

// ---------------- fused per-chunk transpose + K-norm + Beta ----------------
__global__ __launch_bounds__(256) void transpose_norm(
    unsigned short* __restrict__ Kb, const unsigned short* __restrict__ Vb,
    const float* __restrict__ Wbeta, const float* __restrict__ bbeta,
    float* __restrict__ Beta,
    unsigned short* __restrict__ KT, unsigned short* __restrict__ VT)
{
  __shared__ __align__(16) unsigned short Kc[64 * 520];
  int cb = blockIdx.x & 255, tid = threadIdx.x;
  bool isK = blockIdx.x < 256;
  unsigned short* dst = (isK ? KT : VT) + (size_t)cb * 32768;
  if (isK) {
    int lane = tid & 63, w = tid >> 6;
    const float* wb = Wbeta + lane * 8;
    #pragma unroll
    for (int i = 0; i < 16; ++i) {
      int row = w * 16 + i;
      unsigned short* kp = Kb + ((size_t)cb * 64 + row) * 512 + lane * 8;
      uint4 raw = *(uint4*)kp;
      float kv[8]; unpack8(raw, kv);
      float ss = 0.f;
      #pragma unroll
      for (int m = 0; m < 8; ++m) ss += kv[m] * kv[m];
      ss = wave_allreduce(ss);
      float inv = 1.0f / fmaxf(sqrtf(ss), 1e-12f);
      float dotp = 0.f;
      #pragma unroll
      for (int m = 0; m < 8; ++m) { kv[m] *= inv; dotp += kv[m] * wb[m]; }
      uint4 o;
      o.x = f2bf(kv[0]) | ((unsigned)f2bf(kv[1]) << 16);
      o.y = f2bf(kv[2]) | ((unsigned)f2bf(kv[3]) << 16);
      o.z = f2bf(kv[4]) | ((unsigned)f2bf(kv[5]) << 16);
      o.w = f2bf(kv[6]) | ((unsigned)f2bf(kv[7]) << 16);
      *(uint4*)kp = o;                                  // normalized K back to global (for gram)
      *(uint4*)&Kc[row * 520 + lane * 8] = o;           // and into LDS for the transpose
      dotp = wave_allreduce(dotp);
      if (lane == 0) Beta[cb * 64 + row] = 1.0f / (1.0f + expf(-(dotp + bbeta[0])));
    }
  } else {
    const unsigned short* src = Vb + (size_t)cb * 64 * 512;
    #pragma unroll
    for (int it = 0; it < 16; ++it) {
      int e = it * 2048 + tid * 8;
      int row = e >> 9, col = e & 511;
      *(uint4*)&Kc[row * 520 + col] = *(const uint4*)&src[row * 512 + col];
    }
  }
  __syncthreads();
  #pragma unroll
  for (int it = 0; it < 16; ++it) {
    int e = it * 2048 + tid * 8;
    int dk = e >> 6, t0 = e & 63;
    uint4 o;
    unsigned short tv[8];
    #pragma unroll
    for (int u = 0; u < 8; ++u) tv[u] = Kc[(t0 + u) * 520 + dk];
    o.x = tv[0] | ((unsigned)tv[1] << 16);
    o.y = tv[2] | ((unsigned)tv[3] << 16);
    o.z = tv[4] | ((unsigned)tv[5] << 16);
    o.w = tv[6] | ((unsigned)tv[7] << 16);
    *(uint4*)&dst[e] = o;
  }
}

// ---------------- fused Gram + Tinv ----------------
__global__ __launch_bounds__(256) void gram_tinv(
    const unsigned short* __restrict__ Qb, const unsigned short* __restrict__ Kb,
    const float* __restrict__ Beta, unsigned short* __restrict__ Msb,
    unsigned short* __restrict__ Tib)
{
  __shared__ float Af[64 * 68];    // 17.4 KB
  __shared__ float XT[64 * 68];    // 17.4 KB
  int cb = blockIdx.x, tid = threadIdx.x, lane = tid & 63, w = tid >> 6;
  int lr = lane & 15, quad = lane >> 4;
  if (tid < 64) {
    *(float4*)&Af[tid * 68 + 64] = (float4){0.f,0.f,0.f,0.f};
  }
  const unsigned short* kc = Kb + (size_t)cb * 64 * 512;
  const unsigned short* qc = Qb + (size_t)cb * 64 * 512;
  floatx4 accK[4], accQ[4];
  #pragma unroll
  for (int nt = 0; nt < 4; ++nt) { accK[nt] = (floatx4){0,0,0,0}; accQ[nt] = (floatx4){0,0,0,0}; }
  #pragma unroll
  for (int ks = 0; ks < 16; ++ks) {
    short8 ak = *(const short8*)&kc[(w * 16 + lr) * 512 + ks * 32 + quad * 8];
    short8 aq = *(const short8*)&qc[(w * 16 + lr) * 512 + ks * 32 + quad * 8];
    short8 bk[4];
    #pragma unroll
    for (int nt = 0; nt < 4; ++nt)
      bk[nt] = *(const short8*)&kc[(nt * 16 + lr) * 512 + ks * 32 + quad * 8];
    #pragma unroll
    for (int nt = 0; nt < 4; ++nt) {
      accK[nt] = __builtin_amdgcn_mfma_f32_16x16x32_bf16(ak, bk[nt], accK[nt], 0, 0, 0);
      accQ[nt] = __builtin_amdgcn_mfma_f32_16x16x32_bf16(aq, bk[nt], accQ[nt], 0, 0, 0);
    }
  }
  #pragma unroll
  for (int nt = 0; nt < 4; ++nt)
    #pragma unroll
    for (int r = 0; r < 4; ++r) {
      int t = w * 16 + quad * 4 + r;
      int j = nt * 16 + lr;
      float bt = Beta[cb * 64 + t];
      Af[t * 68 + j] = (j < t) ? bt * accK[nt][r] : 0.f;
      Msb[(size_t)cb * 4096 + t * 64 + j] = f2bf((j <= t) ? accQ[nt][r] : 0.f);
    }
  __syncthreads();
  if (tid < 64) {
    int l = tid;
    float bl = Beta[cb * 64 + l];
    unsigned short* To = Tib + (size_t)cb * 4096;
    float* Xr = XT + l * 68;
    #pragma unroll
    for (int j = 0; j < 68; j += 4) *(float4*)&Xr[j] = (float4){0.f,0.f,0.f,0.f};
    for (int t = 0; t < 64; ++t) {
      const float* Ar = Af + t * 68;
      float p0 = 0.f, p1 = 0.f, p2 = 0.f, p3 = 0.f;
      for (int jb = 0; jb < t; jb += 4) {
        float4 xv = *(const float4*)&Xr[jb];
        float4 av = *(const float4*)&Ar[jb];
        p0 = fmaf(av.x, xv.x, p0); p1 = fmaf(av.y, xv.y, p1);
        p2 = fmaf(av.z, xv.z, p2); p3 = fmaf(av.w, xv.w, p3);
      }
      float y = ((l == t) ? 1.f : 0.f) - (p0 + p1) - (p2 + p3);
      Xr[t] = y;
      To[t * 64 + l] = f2bf(y * bl);
    }
  }
}

// ---------------- Wneg = -Tinvbeta*K, Ubar = Tinvbeta*V (dd-half split, 2 blocks/CU) ----------------
__global__ __launch_bounds__(256) void wu_kernel(
    const unsigned short* __restrict__ Tib, const unsigned short* __restrict__ KT,
    const unsigned short* __restrict__ VT, unsigned short* __restrict__ Wneg,
    unsigned short* __restrict__ Ubar)
{
  __shared__ __align__(16) unsigned short WL[64 * 256];   // 32 KB
  __shared__ __align__(16) unsigned short UL[64 * 256];   // 32 KB
  int cb = blockIdx.x >> 1, half = blockIdx.x & 1;
  int tid = threadIdx.x, lane = tid & 63, w = tid >> 6;
  int lr = lane & 15, quad = lane >> 4;
  short8 af0 = *(const short8*)&Tib[(size_t)cb * 4096 + (w * 16 + lr) * 64 + quad * 8];
  short8 af1 = *(const short8*)&Tib[(size_t)cb * 4096 + (w * 16 + lr) * 64 + 32 + quad * 8];
  const unsigned short* ktc = KT + (size_t)cb * 32768 + lr * 64 + quad * 8;
  const unsigned short* vtc = VT + (size_t)cb * 32768 + lr * 64 + quad * 8;
  int tbase = w * 16 + quad * 4;
  int nt0 = half * 16;
  #pragma unroll 4
  for (int ntl = 0; ntl < 16; ++ntl) {
    int nt = nt0 + ntl;
    short8 bk0 = *(const short8*)(ktc + nt * 1024);
    short8 bk1 = *(const short8*)(ktc + nt * 1024 + 32);
    short8 bv0 = *(const short8*)(vtc + nt * 1024);
    short8 bv1 = *(const short8*)(vtc + nt * 1024 + 32);
    floatx4 z = (floatx4){0.f,0.f,0.f,0.f};
    floatx4 aw = __builtin_amdgcn_mfma_f32_16x16x32_bf16(af0, bk0, z, 0, 0, 0);
    aw = __builtin_amdgcn_mfma_f32_16x16x32_bf16(af1, bk1, aw, 0, 0, 0);
    floatx4 au = __builtin_amdgcn_mfma_f32_16x16x32_bf16(af0, bv0, z, 0, 0, 0);
    au = __builtin_amdgcn_mfma_f32_16x16x32_bf16(af1, bv1, au, 0, 0, 0);
    int bi = ntl * 2 + (lr >> 3);
    int lo = lr & 7;
    #pragma unroll
    for (int r = 0; r < 4; ++r) {
      int tt = tbase + r;
      int bis = bi ^ (tt & 7);
      WL[tt * 256 + bis * 8 + lo] = f2bf(-aw[r]);
      UL[tt * 256 + bis * 8 + lo] = f2bf(au[r]);
    }
  }
  __syncthreads();
  unsigned short* wd = Wneg + (size_t)cb * 32768 + half * 256;
  unsigned short* ud = Ubar + (size_t)cb * 32768 + half * 256;
  #pragma unroll
  for (int it = 0; it < 8; ++it) {
    int e = it * 2048 + tid * 8;
    int row = e >> 8, col = e & 255;
    int bis = (col >> 3) ^ (row & 7);
    *(uint4*)&wd[(size_t)row * 512 + col] = *(const uint4*)&WL[row * 256 + bis * 8];
    *(uint4*)&ud[(size_t)row * 512 + col] = *(const uint4*)&UL[row * 256 + bis * 8];
  }
}

// ---------------- sequential chunk scan with rolling register prefetch (r1/r10-verified, ~188us) ----------------
// PARKED: the ~188us floor = 54 loads/wave x ~250cy L2 latency, serialized by
// compiler load-sinking. Five HIP-level levers (sched_barrier, opaque asm,
// mem-fence, LDS-staging, keep-alive) all failed to break it; do not retry.
__global__ __launch_bounds__(256, 1) void seq_kernel(
    const unsigned short* __restrict__ Wneg, const unsigned short* __restrict__ Qb,
    const unsigned short* __restrict__ Ubar, const unsigned short* __restrict__ Msb,
    const unsigned short* __restrict__ KT, unsigned short* __restrict__ Ob)
{
  __shared__ __align__(16) unsigned short Sb[16 * 520];
  __shared__ __align__(16) unsigned short Ut[16 * 72];
  int blk = blockIdx.x;
  int b = blk & 7, vs = blk >> 3;      // batch pinned to XCD b for L2 sharing
  int vg0 = vs * 16;
  int tid = threadIdx.x, lane = tid & 63, w = tid >> 6;
  int lr = lane & 15, quad = lane >> 4;

  floatx4 sacc[8];
  #pragma unroll
  for (int nt = 0; nt < 8; ++nt) sacc[nt] = (floatx4){0.f,0.f,0.f,0.f};

  short8 wn[16], qf[16], kt[16], ms[2];
  unsigned short ub[4];

  auto LD_WQ = [&](int cb) {
    const unsigned short* wr = Wneg + ((size_t)cb * 64 + w * 16 + lr) * 512 + quad * 8;
    const unsigned short* qr = Qb   + ((size_t)cb * 64 + w * 16 + lr) * 512 + quad * 8;
    #pragma unroll
    for (int ks = 0; ks < 16; ++ks) {
      wn[ks] = *(const short8*)(wr + ks * 32);
      qf[ks] = *(const short8*)(qr + ks * 32);
    }
  };
  auto LD_KM = [&](int cb) {
    const unsigned short* kr = KT + (size_t)cb * 32768 + (w * 128 + lr) * 64 + quad * 8;
    #pragma unroll
    for (int nt = 0; nt < 8; ++nt) {
      kt[nt * 2 + 0] = *(const short8*)(kr + nt * 1024);
      kt[nt * 2 + 1] = *(const short8*)(kr + nt * 1024 + 32);
    }
    const unsigned short* mr = Msb + (size_t)cb * 4096 + (w * 16 + lr) * 64 + quad * 8;
    ms[0] = *(const short8*)(mr);
    ms[1] = *(const short8*)(mr + 32);
  };
  auto LD_UB = [&](int cb) {
    const unsigned short* ur = Ubar + ((size_t)cb * 64 + w * 16 + quad * 4) * 512 + vg0 + lr;
    #pragma unroll
    for (int r = 0; r < 4; ++r) ub[r] = ur[r * 512];
  };

  int cb0 = b * NCHB;
  LD_WQ(cb0); LD_KM(cb0); LD_UB(cb0);

  for (int ch = 0; ch < NCHB; ++ch) {
    int cb = cb0 + ch;
    int cbn = cb0 + (ch + 1 < NCHB ? ch + 1 : ch);
    // phase 0: stage S^T (bf16) into LDS
    #pragma unroll
    for (int nt = 0; nt < 8; ++nt)
      #pragma unroll
      for (int r = 0; r < 4; ++r)
        Sb[(quad * 4 + r) * 520 + w * 128 + nt * 16 + lr] = f2bf(sacc[nt][r]);
    __syncthreads();
    // phase 1: U-GEMM and Q*S^T interleaved (4 independent accumulator chains)
    floatx4 du0, du1, do0, do1;
    #pragma unroll
    for (int r = 0; r < 4; ++r) du0[r] = bf2f(ub[r]);
    du1 = (floatx4){0.f,0.f,0.f,0.f};
    do0 = (floatx4){0.f,0.f,0.f,0.f};
    do1 = (floatx4){0.f,0.f,0.f,0.f};
    #pragma unroll
    for (int ks = 0; ks < 16; ++ks) {
      short8 sb = *(const short8*)&Sb[lr * 520 + ks * 32 + quad * 8];
      if (ks & 1) {
        du1 = __builtin_amdgcn_mfma_f32_16x16x32_bf16(wn[ks], sb, du1, 0, 0, 0);
        do1 = __builtin_amdgcn_mfma_f32_16x16x32_bf16(qf[ks], sb, do1, 0, 0, 0);
      } else {
        du0 = __builtin_amdgcn_mfma_f32_16x16x32_bf16(wn[ks], sb, du0, 0, 0, 0);
        do0 = __builtin_amdgcn_mfma_f32_16x16x32_bf16(qf[ks], sb, do0, 0, 0, 0);
      }
    }
    #pragma unroll
    for (int r = 0; r < 4; ++r)
      Ut[lr * 72 + w * 16 + quad * 4 + r] = f2bf(du0[r] + du1[r]);
    LD_WQ(cbn);                      // prefetch: wn/qf dead
    LD_UB(cbn);                      // prefetch: ub consumed into du0
    __syncthreads();
    // phase 2: Ms*U into O, S += U^T*K
    short8 a2_0 = *(const short8*)&Ut[lr * 72 + quad * 8];
    short8 a2_1 = *(const short8*)&Ut[lr * 72 + 32 + quad * 8];
    do0 = __builtin_amdgcn_mfma_f32_16x16x32_bf16(ms[0], a2_0, do0, 0, 0, 0);
    do1 = __builtin_amdgcn_mfma_f32_16x16x32_bf16(ms[1], a2_1, do1, 0, 0, 0);
    #pragma unroll
    for (int nt = 0; nt < 8; ++nt) {
      sacc[nt] = __builtin_amdgcn_mfma_f32_16x16x32_bf16(a2_0, kt[nt * 2 + 0], sacc[nt], 0, 0, 0);
      sacc[nt] = __builtin_amdgcn_mfma_f32_16x16x32_bf16(a2_1, kt[nt * 2 + 1], sacc[nt], 0, 0, 0);
    }
    {
      unsigned short* ob = Ob + ((size_t)cb * 64 + w * 16 + quad * 4) * 512 + vg0 + lr;
      #pragma unroll
      for (int r = 0; r < 4; ++r) ob[r * 512] = f2bf(do0[r] + do1[r]);
    }
    LD_KM(cbn);                      // prefetch: kt/ms dead
  }
}

extern "C" void kernel_launch(void* const* d_in, const int* in_sizes, int n_in,
                              void* d_out, int out_size, void* d_ws, size_t ws_size,
                              hipStream_t stream) {
  const float* x     = (const float*)d_in[0];
  const float* Wq    = (const float*)d_in[1];
  const float* bq    = (const float*)d_in[2];
  const float* Wk    = (const float*)d_in[3];
  const float* bk    = (const float*)d_in[4];
  const float* Wv    = (const float*)d_in[5];
  const float* bv    = (const float*)d_in[6];
  const float* Wbeta = (const float*)d_in[7];
  const float* bbeta = (const float*)d_in[8];
  const float* Wo    = (const float*)d_in[9];
  const float* bo    = (const float*)d_in[10];

  const size_t NE = (size_t)M_ROWS * D;   // 8,388,608
  const size_t DD = (size_t)D * D;
  unsigned short* Qb  = (unsigned short*)d_ws;
  unsigned short* Kb  = Qb + NE;          // later: Ubar
  unsigned short* Vb  = Kb + NE;          // later: O
  unsigned short* Xb  = Vb + NE;          // x bf16; later: Wneg
  unsigned short* Wqb = Xb + NE;          // Wqb|Wkb|Wvb|Wob contiguous
  unsigned short* Wkb = Wqb + DD;
  unsigned short* Wvb = Wkb + DD;
  unsigned short* Wob = Wvb + DD;
  float* Beta = (float*)(Wob + DD);                        // 16384 f32
  unsigned short* KT  = (unsigned short*)(Beta + M_ROWS);  // NE shorts
  float* Abuf = (float*)(KT + NE);                         // (unused; layout kept)
  unsigned short* Msb = (unsigned short*)(Abuf + (size_t)NCHUNK * 4096);
  unsigned short* Tib = Msb + (size_t)NCHUNK * 4096;
  unsigned short* VT  = Tib + (size_t)NCHUNK * 4096;       // NE shorts; total ~106 MB

  cast_all<<<4608, 256, 0, stream>>>(x, Wq, Wk, Wv, Wo, Xb, Wqb);

  dim3 gq(12, M_ROWS / BM);
  gemm_qkv<<<gq, 256, 0, stream>>>(Xb, Wqb, bq, bk, bv, Qb);

  transpose_norm<<<2 * NCHUNK, 256, 0, stream>>>(Kb, Vb, Wbeta, bbeta, Beta, KT, VT);
  gram_tinv<<<NCHUNK, 256, 0, stream>>>(Qb, Kb, Beta, Msb, Tib);
  wu_kernel<<<2 * NCHUNK, 256, 0, stream>>>(Tib, KT, VT, /*Wneg=*/Xb, /*Ubar=*/Kb);

  seq_kernel<<<NCHUNK, 256, 0, stream>>>(/*Wneg=*/Xb, Qb, /*Ubar=*/Kb, Msb, KT, /*O=*/Vb);

  dim3 gg(D / BN, M_ROWS / BM);  // (4, 128)
  gemm_nt<false><<<gg, 256, 0, stream>>>(Vb, Wob, bo, (float*)d_out, M_ROWS, D, D);
}